// Round 5
// baseline (981.625 us; speedup 1.0000x reference)
//
#include <hip/hip_runtime.h>
#include <hip/hip_bf16.h>

#define E_EDGES 131072
#define NNODES  8192
#define NB      16384   // N_NODES * BATCH rows
#define HID     256
#define EDIM    64
#define MLPH    512
#define OUTD    128
#define NIT     3
#define RB      32      // rows per node_update block (16 nodes x 2 batches)

typedef short s16x4 __attribute__((ext_vector_type(4)));
typedef short s16x8 __attribute__((ext_vector_type(8)));
typedef float f32x4 __attribute__((ext_vector_type(4)));

__device__ __forceinline__ short f2bf(float f){
  unsigned int x = __builtin_bit_cast(unsigned int, f);
  x += 0x7fffu + ((x >> 16) & 1u);          // RNE
  return (short)(x >> 16);
}
__device__ __forceinline__ float bf2f(short s){
  unsigned int x = ((unsigned int)(unsigned short)s) << 16;
  return __builtin_bit_cast(float, x);
}
__device__ __forceinline__ void gload_lds16(const void* g, void* l){
  __builtin_amdgcn_global_load_lds(
      (const __attribute__((address_space(1))) void*)g,
      (__attribute__((address_space(3))) void*)l, 16, 0, 0);
}
#define MFMA16(a,b,c) __builtin_amdgcn_mfma_f32_16x16x32_bf16((a),(b),(c),0,0,0)

// ===========================================================================
// Fused node update (one block = 32 rows = 16 nodes).
//   stage: Sl <- S[grow0..+32][512] (global, pre-swizzled source)
//   A: acc = m + deg*b2 + S@W2  -> m (global, PH<2), Ms (bf16 LDS)
//   B+C: Gr,Gz = [m|h]@BtRZ (one A-pass)
//   e1: r,z; Xs <- bf16(r*h)
//   D: Gw = [m|rh]@BtHW
//   e2: h' = (1-z)h + z*tanh(Gw+bh) -> h, Ms        [PH2: Hf]
//   E: P = h'@BtP (PH<2)   |   PH==2: in-LDS readout partial -> atomic g
// A-operands LDS-resident (XOR-16B swizzle, 2-way = free); B-operands load
// as per-lane 16B global frags (L2-hot, full-line consumption) -> ~7 barriers.
// PH: 0 = first iter (h=0, m=0: K=256 gates, no m/h reads), 1 = mid, 2 = last.
// ===========================================================================
template<int PH>
__global__ __launch_bounds__(256, 2)
void node_update(const short* __restrict__ S, short* __restrict__ Pout,
                 float* __restrict__ m, float* __restrict__ h,
                 float* __restrict__ g,
                 const short* __restrict__ BtW2, const short* __restrict__ BtRZ,
                 const short* __restrict__ BtHW, const short* __restrict__ BtP,
                 const int* __restrict__ deg, const float* __restrict__ b2,
                 const float* __restrict__ br, const float* __restrict__ bz,
                 const float* __restrict__ bh)
{
  __shared__ __align__(16) char lds[65536];
  short* Sl = (short*)lds;              // [32][512] bf16 swizzled (32KB)
  short* Ms = (short*)(lds + 32768);    // [32][256] bf16 swizzled
  short* Xs = (short*)(lds + 49152);    // [32][256] bf16 swizzled
  float* Hf = (float*)lds;              // [32][256] f32 overlay (PH2, Sl dead)

  const int tid = threadIdx.x;
  const int w  = tid >> 6, l = tid & 63;
  const int lr = l & 15, lg = l >> 4;
  const int grow0 = blockIdx.x * RB;

  auto rdS   = [&](int row, int c){ return row * 512 + (c ^ ((row & 7) << 3)); };
  auto rd256 = [&](int row, int c){ return row * 256 + (c ^ ((row & 7) << 3)); };

  // ---- stage Sl from global S (linear LDS dest, pre-swizzled source) ----
#pragma unroll
  for (int i = 0; i < 8; ++i){
    int u = i * 256 + tid;
    int row = u >> 6, uc = u & 63;           // 64 x 16B units per row
    const short* gp = S + (size_t)(grow0 + row) * 512 + ((uc ^ (row & 7)) << 3);
    gload_lds16(gp, (char*)Sl + i * 4096 + w * 1024);
  }

  // ---- h into regs, acc init = m + deg*b2; Xs <- bf16(h) ----
  f32x4 hv[2][4], acc[2][4];
#pragma unroll
  for (int i = 0; i < 2; ++i)
#pragma unroll
    for (int j = 0; j < 4; ++j)
#pragma unroll
      for (int r = 0; r < 4; ++r){
        int rl = i*16 + lg*4 + r, colp = w*64 + j*16 + lr;
        size_t gi = (size_t)(grow0 + rl) * 256 + colp;
        float base = (float)deg[(grow0 + rl) >> 1] * b2[colp];
        if (PH > 0){ base += m[gi]; hv[i][j][r] = h[gi]; }
        else hv[i][j][r] = 0.f;
        acc[i][j][r] = base;
      }
  if (PH > 0){
#pragma unroll
    for (int i = 0; i < 2; ++i)
#pragma unroll
      for (int j = 0; j < 4; ++j)
#pragma unroll
        for (int r = 0; r < 4; ++r){
          int rl = i*16 + lg*4 + r, colp = w*64 + j*16 + lr;
          Xs[rd256(rl, colp)] = f2bf(hv[i][j][r]);
        }
  }
  __syncthreads();                         // Sl + Xs(hb) visible

  // ---- Phase A: acc += S @ W2 (K=512) ----
#pragma unroll 4
  for (int c = 0; c < 16; ++c){
    s16x8 a0 = *(const s16x8*)(Sl + rdS(lr,      c*32 + lg*8));
    s16x8 a1 = *(const s16x8*)(Sl + rdS(16 + lr, c*32 + lg*8));
#pragma unroll
    for (int j = 0; j < 4; ++j){
      s16x8 bb = *(const s16x8*)(BtW2 + (size_t)(w*64 + j*16 + lr) * 512 + c*32 + lg*8);
      acc[0][j] = MFMA16(a0, bb, acc[0][j]);
      acc[1][j] = MFMA16(a1, bb, acc[1][j]);
    }
  }
#pragma unroll
  for (int i = 0; i < 2; ++i)
#pragma unroll
    for (int j = 0; j < 4; ++j)
#pragma unroll
      for (int r = 0; r < 4; ++r){
        int rl = i*16 + lg*4 + r, colp = w*64 + j*16 + lr;
        float v = acc[i][j][r];
        if (PH < 2) m[(size_t)(grow0 + rl) * 256 + colp] = v;
        Ms[rd256(rl, colp)] = f2bf(v);
      }
  __syncthreads();                         // Ms(m_bf) visible

  // ---- Phase B+C: Gr, Gz in one A-pass ----
  f32x4 Gr[2][4], Gz[2][4];
#pragma unroll
  for (int i = 0; i < 2; ++i)
#pragma unroll
    for (int j = 0; j < 4; ++j){ Gr[i][j] = (f32x4){0.f,0.f,0.f,0.f}; Gz[i][j] = (f32x4){0.f,0.f,0.f,0.f}; }

  auto gemmRZ = [&](const short* Ab, int koff){
#pragma unroll 2
    for (int c = 0; c < 8; ++c){
      s16x8 a0 = *(const s16x8*)(Ab + rd256(lr,      c*32 + lg*8));
      s16x8 a1 = *(const s16x8*)(Ab + rd256(16 + lr, c*32 + lg*8));
#pragma unroll
      for (int j = 0; j < 4; ++j){
        int colr = w*64 + j*16 + lr;
        s16x8 b_r = *(const s16x8*)(BtRZ + (size_t)colr         * 512 + koff + c*32 + lg*8);
        s16x8 b_z = *(const s16x8*)(BtRZ + (size_t)(256 + colr) * 512 + koff + c*32 + lg*8);
        Gr[0][j] = MFMA16(a0, b_r, Gr[0][j]);
        Gr[1][j] = MFMA16(a1, b_r, Gr[1][j]);
        Gz[0][j] = MFMA16(a0, b_z, Gz[0][j]);
        Gz[1][j] = MFMA16(a1, b_z, Gz[1][j]);
      }
    }
  };
  gemmRZ(Ms, 0);
  if (PH > 0) gemmRZ(Xs, 256);

  // ---- e1: r, z; Xs <- bf16(r*h) ----
  f32x4 zz[2][4];
#pragma unroll
  for (int i = 0; i < 2; ++i)
#pragma unroll
    for (int j = 0; j < 4; ++j)
#pragma unroll
      for (int r = 0; r < 4; ++r){
        int colp = w*64 + j*16 + lr;
        zz[i][j][r] = 1.f / (1.f + __expf(-(Gz[i][j][r] + bz[colp])));
      }
  if (PH > 0){
    __syncthreads();                       // B/C's Xs(hb) reads done
#pragma unroll
    for (int i = 0; i < 2; ++i)
#pragma unroll
      for (int j = 0; j < 4; ++j)
#pragma unroll
        for (int r = 0; r < 4; ++r){
          int rl = i*16 + lg*4 + r, colp = w*64 + j*16 + lr;
          float rr = 1.f / (1.f + __expf(-(Gr[i][j][r] + br[colp])));
          Xs[rd256(rl, colp)] = f2bf(rr * hv[i][j][r]);
        }
    __syncthreads();                       // Xs(rh) visible
  }

  // ---- Phase D: Gw = [m|rh] @ BtHW ----
  f32x4 Gw[2][4];
#pragma unroll
  for (int i = 0; i < 2; ++i)
#pragma unroll
    for (int j = 0; j < 4; ++j) Gw[i][j] = (f32x4){0.f,0.f,0.f,0.f};
  auto gemmHW = [&](const short* Ab, int koff){
#pragma unroll 2
    for (int c = 0; c < 8; ++c){
      s16x8 a0 = *(const s16x8*)(Ab + rd256(lr,      c*32 + lg*8));
      s16x8 a1 = *(const s16x8*)(Ab + rd256(16 + lr, c*32 + lg*8));
#pragma unroll
      for (int j = 0; j < 4; ++j){
        s16x8 bb = *(const s16x8*)(BtHW + (size_t)(w*64 + j*16 + lr) * 512 + koff + c*32 + lg*8);
        Gw[0][j] = MFMA16(a0, bb, Gw[0][j]);
        Gw[1][j] = MFMA16(a1, bb, Gw[1][j]);
      }
    }
  };
  gemmHW(Ms, 0);
  if (PH > 0) gemmHW(Xs, 256);
  __syncthreads();                         // D's Ms reads done

  // ---- e2: h' ----
#pragma unroll
  for (int i = 0; i < 2; ++i)
#pragma unroll
    for (int j = 0; j < 4; ++j)
#pragma unroll
      for (int r = 0; r < 4; ++r){
        int rl = i*16 + lg*4 + r, colp = w*64 + j*16 + lr;
        float ht = tanhf(Gw[i][j][r] + bh[colp]);
        float z  = zz[i][j][r];
        float hn = (1.f - z) * hv[i][j][r] + z * ht;
        if (PH < 2){
          h[(size_t)(grow0 + rl) * 256 + colp] = hn;
          Ms[rd256(rl, colp)] = f2bf(hn);
        } else {
          Hf[rl * 256 + colp] = hn;
        }
      }
  __syncthreads();                         // Ms(h') / Hf visible

  if (PH < 2){
    // ---- Phase E: P = h' @ BtP, 4 panels of 256 cols ----
    for (int pn = 0; pn < 4; ++pn){
      f32x4 pa0[4], pa1[4];
#pragma unroll
      for (int j = 0; j < 4; ++j){ pa0[j] = (f32x4){0.f,0.f,0.f,0.f}; pa1[j] = (f32x4){0.f,0.f,0.f,0.f}; }
#pragma unroll 2
      for (int c = 0; c < 8; ++c){
        s16x8 a0 = *(const s16x8*)(Ms + rd256(lr,      c*32 + lg*8));
        s16x8 a1 = *(const s16x8*)(Ms + rd256(16 + lr, c*32 + lg*8));
#pragma unroll
        for (int j = 0; j < 4; ++j){
          s16x8 bb = *(const s16x8*)(BtP + (size_t)(pn*256 + w*64 + j*16 + lr) * 256 + c*32 + lg*8);
          pa0[j] = MFMA16(a0, bb, pa0[j]);
          pa1[j] = MFMA16(a1, bb, pa1[j]);
        }
      }
#pragma unroll
      for (int j = 0; j < 4; ++j)
#pragma unroll
        for (int r = 0; r < 4; ++r){
          int colp = w*64 + j*16 + lr;
          Pout[(size_t)(grow0 + lg*4 + r)      * 1024 + pn*256 + colp] = f2bf(pa0[j][r]);
          Pout[(size_t)(grow0 + 16 + lg*4 + r) * 1024 + pn*256 + colp] = f2bf(pa1[j][r]);
        }
    }
  } else {
    // ---- readout partial: g[b*256+col] += sum over node rows ----
    float s0 = 0.f, s1 = 0.f;
#pragma unroll
    for (int rr = 0; rr < 16; ++rr){
      s0 += Hf[(2*rr)     * 256 + tid];
      s1 += Hf[(2*rr + 1) * 256 + tid];
    }
    atomicAdd(&g[tid], s0);
    atomicAdd(&g[256 + tid], s1);
  }
}

// ---------------------------------------------------------------------------
// E1 gather GEMM (chunked): E1[R] = ebf[eid[p0+(R>>1)]*2+(R&1)] @ BtE + b1,
// R relative to chunk. K=64 single step. Output stays L3-hot for edge_kernel.
// ---------------------------------------------------------------------------
__global__ __launch_bounds__(256, 3)
void e1_gemm(const short* __restrict__ A, const short* __restrict__ Bt,
             short* __restrict__ E1, const float* __restrict__ bias,
             const int* __restrict__ gat, const int* __restrict__ rs,
             int node0, int node1)
{
  __shared__ __align__(16) short As[128 * 64];
  __shared__ __align__(16) short Bs[128 * 64];

  const int p0 = rs[node0];
  const int mrows = 2 * (rs[node1] - p0);
  if ((int)blockIdx.x * 128 >= mrows) return;

  const int t  = threadIdx.x;
  const int w  = t >> 6, l = t & 63;
  const int lr = l & 15, lg = l >> 4;
  const int wr = w >> 1, wc = w & 1;
  const int browbase = blockIdx.x * 128;
  const int bcolbase = blockIdx.y * 128;
  const int srow = t >> 3;
  const int scol = (t & 7) * 8;

  f32x4 acc[4][4];
#pragma unroll
  for (int mm = 0; mm < 4; ++mm)
#pragma unroll
    for (int n = 0; n < 4; ++n) acc[mm][n] = (f32x4){0.f,0.f,0.f,0.f};

#pragma unroll
  for (int i = 0; i < 4; ++i){
    int R = browbase + srow + i * 32;
    if (R >= mrows) R = mrows - 1;
    int e = gat[p0 + (R >> 1)];
    gload_lds16(A + (size_t)(e * 2 + (R & 1)) * EDIM + scol,
                (char*)As + w * 1024 + i * 4096);
  }
#pragma unroll
  for (int i = 0; i < 4; ++i)
    gload_lds16(Bt + (size_t)(bcolbase + srow + i * 32) * EDIM + scol,
                (char*)Bs + w * 1024 + i * 4096);
  __syncthreads();

#pragma unroll
  for (int kk = 0; kk < 2; ++kk){
    s16x8 a[4], b[4];
#pragma unroll
    for (int mm = 0; mm < 4; ++mm)
      a[mm] = *(const s16x8*)(As + (wr*64 + mm*16 + lr) * 64 + kk*32 + lg*8);
#pragma unroll
    for (int n = 0; n < 4; ++n)
      b[n] = *(const s16x8*)(Bs + (wc*64 + n*16 + lr) * 64 + kk*32 + lg*8);
#pragma unroll
    for (int mm = 0; mm < 4; ++mm)
#pragma unroll
      for (int n = 0; n < 4; ++n)
        acc[mm][n] = MFMA16(a[mm], b[n], acc[mm][n]);
  }
#pragma unroll
  for (int mm = 0; mm < 4; ++mm){
    int orow0 = browbase + wr*64 + mm*16 + lg*4;
#pragma unroll
    for (int n = 0; n < 4; ++n){
      int ocol = bcolbase + wc*64 + n*16 + lr;
#pragma unroll
      for (int r = 0; r < 4; ++r){
        int orow = orow0 + r;
        if (orow < mrows)
          E1[(size_t)orow * MLPH + ocol] = f2bf(acc[mm][n][r] + bias[ocol]);
      }
    }
  }
}

// ---------------------------------------------------------------------------
// Per-node CSR edge kernel: S[n] = sum_{e: dst=n} relu(P1[n] + P2[src] + E1[e])
// E1 indexed relative to chunk base (p - rs[node0]).
// ---------------------------------------------------------------------------
template<bool USE_P>
__global__ __launch_bounds__(256)
void edge_kernel(const short* __restrict__ P, const short* __restrict__ E1,
                 const int* __restrict__ csr_src, const int* __restrict__ row_start,
                 short* __restrict__ S, int node0)
{
  const int n = node0 + blockIdx.x;
  const int t = threadIdx.x;
  const int b = t >> 7;
  const int j = (t & 127) << 2;
  const int p0 = row_start[node0];
  const int ps = row_start[n], pe = row_start[n + 1];

  float p10 = 0.f, p11 = 0.f, p12 = 0.f, p13 = 0.f;
  if (USE_P){
    s16x4 t1 = *(const s16x4*)(P + (size_t)(n * 2 + b) * 1024 + j);
    p10 = bf2f(t1[0]); p11 = bf2f(t1[1]); p12 = bf2f(t1[2]); p13 = bf2f(t1[3]);
  }
  float a0 = 0.f, a1 = 0.f, a2 = 0.f, a3 = 0.f;
  for (int p = ps; p < pe; ++p){
    s16x4 v1 = *(const s16x4*)(E1 + (size_t)((p - p0) * 2 + b) * 512 + j);
    float x0 = p10 + bf2f(v1[0]);
    float x1 = p11 + bf2f(v1[1]);
    float x2 = p12 + bf2f(v1[2]);
    float x3 = p13 + bf2f(v1[3]);
    if (USE_P){
      int src = csr_src[p];
      s16x4 v2 = *(const s16x4*)(P + (size_t)(src * 2 + b) * 1024 + 512 + j);
      x0 += bf2f(v2[0]); x1 += bf2f(v2[1]); x2 += bf2f(v2[2]); x3 += bf2f(v2[3]);
    }
    a0 += fmaxf(x0, 0.f); a1 += fmaxf(x1, 0.f);
    a2 += fmaxf(x2, 0.f); a3 += fmaxf(x3, 0.f);
  }
  s16x4 o; o[0] = f2bf(a0); o[1] = f2bf(a1); o[2] = f2bf(a2); o[3] = f2bf(a3);
  *(s16x4*)(S + (size_t)(n * 2 + b) * 512 + j) = o;
}

// --------------------------- ef -> bf16 conversion -------------------------
__global__ __launch_bounds__(256)
void cvt_ef(const float* __restrict__ ef, short* __restrict__ ebf){
  size_t i = (size_t)(blockIdx.x * 256 + threadIdx.x) * 8;
  f32x4 f0 = *(const f32x4*)(ef + i);
  f32x4 f1 = *(const f32x4*)(ef + i + 4);
  s16x8 o;
  o[0]=f2bf(f0[0]); o[1]=f2bf(f0[1]); o[2]=f2bf(f0[2]); o[3]=f2bf(f0[3]);
  o[4]=f2bf(f1[0]); o[5]=f2bf(f1[1]); o[6]=f2bf(f1[2]); o[7]=f2bf(f1[3]);
  *(s16x8*)(ebf + i) = o;
}

// ------------------------------- CSR build ---------------------------------
__global__ void count_kernel(const int* __restrict__ edst, int* __restrict__ counts){
  int e = blockIdx.x * 256 + threadIdx.x;
  if (e < E_EDGES) atomicAdd(&counts[edst[e]], 1);
}
__global__ void scan_kernel(const int* __restrict__ counts, int* __restrict__ row_start,
                            int* __restrict__ cursor){
  __shared__ int sums[1024];
  int t = threadIdx.x;
  int base = t * 8;
  int loc[8]; int s = 0;
#pragma unroll
  for (int i = 0; i < 8; ++i){ loc[i] = s; s += counts[base + i]; }
  sums[t] = s;
  __syncthreads();
  for (int o = 1; o < 1024; o <<= 1){
    int v = sums[t];
    int u = (t >= o) ? sums[t - o] : 0;
    __syncthreads();
    sums[t] = v + u;
    __syncthreads();
  }
  int excl = (t == 0) ? 0 : sums[t - 1];
#pragma unroll
  for (int i = 0; i < 8; ++i){ int v = excl + loc[i]; row_start[base + i] = v; cursor[base + i] = v; }
  if (t == 1023) row_start[NNODES] = sums[1023];
}
__global__ void fill_kernel(const int* __restrict__ edst, const int* __restrict__ esrc,
                            int* __restrict__ cursor, int* __restrict__ csr_eid,
                            int* __restrict__ csr_src){
  int e = blockIdx.x * 256 + threadIdx.x;
  if (e < E_EDGES){
    int pos = atomicAdd(&cursor[edst[e]], 1);
    csr_eid[pos] = e;
    csr_src[pos] = esrc[e];
  }
}

// --------------------------- weight repacking ------------------------------
// BtP [1024][256], BtE [512][64], BtW2 [256][512],
// BtRZ [512][512] (cols r|z, K = W|U), BtHW [256][512] (K = Wh|Uh)
__global__ void prep_weights(const float* __restrict__ W1, const float* __restrict__ W2,
                             const float* __restrict__ Wr, const float* __restrict__ Ur,
                             const float* __restrict__ Wz, const float* __restrict__ Uz,
                             const float* __restrict__ Wh, const float* __restrict__ Uh,
                             short* __restrict__ BtP, short* __restrict__ BtE,
                             short* __restrict__ BtW2, short* __restrict__ BtRZ,
                             short* __restrict__ BtHW)
{
  int id = blockIdx.x * 256 + threadIdx.x;
  if (id < 262144){                       // BtP
    int jj = id >> 8, k = id & 255;
    float v = (jj < 512) ? W1[(size_t)k * 512 + jj] : W1[(size_t)(256 + k) * 512 + (jj - 512)];
    BtP[id] = f2bf(v);
  } else if (id < 294912){                // BtE
    int i2 = id - 262144; int jj = i2 >> 6, c = i2 & 63;
    BtE[i2] = f2bf(W1[(size_t)(512 + c) * 512 + jj]);
  } else if (id < 425984){                // BtW2
    int i2 = id - 294912; int n = i2 >> 9, k = i2 & 511;
    BtW2[i2] = f2bf(W2[(size_t)k * 256 + n]);
  } else if (id < 688128){                // BtRZ
    int i2 = id - 425984; int col = i2 >> 9, k = i2 & 511;
    float v;
    if (col < 256) v = (k < 256) ? Wr[(size_t)k * 256 + col] : Ur[(size_t)(k - 256) * 256 + col];
    else { int c2 = col - 256; v = (k < 256) ? Wz[(size_t)k * 256 + c2] : Uz[(size_t)(k - 256) * 256 + c2]; }
    BtRZ[i2] = f2bf(v);
  } else if (id < 819200){                // BtHW
    int i2 = id - 688128; int col = i2 >> 9, k = i2 & 511;
    float v = (k < 256) ? Wh[(size_t)k * 256 + col] : Uh[(size_t)(k - 256) * 256 + col];
    BtHW[i2] = f2bf(v);
  }
}

// -------------------------------- readout ----------------------------------
__global__ __launch_bounds__(256)
void readout2(const float* __restrict__ g, const float* __restrict__ Wo,
              const float* __restrict__ bo, float* __restrict__ out){
  int t = threadIdx.x;
  int b = t >> 7, o = t & 127;
  float s = bo[o];
  for (int c = 0; c < 256; ++c) s += g[b * 256 + c] * Wo[c * 128 + o];
  out[b * 128 + o] = s;
}

// ===========================================================================
extern "C" void kernel_launch(void* const* d_in, const int* in_sizes, int n_in,
                              void* d_out, int out_size, void* d_ws, size_t ws_size,
                              hipStream_t stream)
{
  const float* ef  = (const float*)d_in[0];
  const float* W1  = (const float*)d_in[1];
  const float* b1  = (const float*)d_in[2];
  const float* W2  = (const float*)d_in[3];
  const float* b2  = (const float*)d_in[4];
  const float* Wr  = (const float*)d_in[5];
  const float* Ur  = (const float*)d_in[6];
  const float* br  = (const float*)d_in[7];
  const float* Wz  = (const float*)d_in[8];
  const float* Uz  = (const float*)d_in[9];
  const float* bz  = (const float*)d_in[10];
  const float* Wh  = (const float*)d_in[11];
  const float* Uh  = (const float*)d_in[12];
  const float* bh  = (const float*)d_in[13];
  const float* Wo  = (const float*)d_in[14];
  const float* bo  = (const float*)d_in[15];
  const int* esrc  = (const int*)d_in[16];
  const int* edst  = (const int*)d_in[17];

  char* base = (char*)d_ws;
  size_t off = 0;
  auto alloc = [&](size_t bytes) -> char* {
    off = (off + 255) & ~(size_t)255;
    char* p = base + off;
    off += bytes;
    return p;
  };
  float* h    = (float*)alloc((size_t)NB * 256 * 4);
  float* m    = (float*)alloc((size_t)NB * 256 * 4);
  short* PA   = (short*)alloc((size_t)NB * 1024 * 2);
  short* PB   = (short*)alloc((size_t)NB * 1024 * 2);
  short* S    = (short*)alloc((size_t)NB * 512 * 2);
  short* ebf  = (short*)alloc((size_t)E_EDGES * 2 * EDIM * 2);
  short* BtP  = (short*)alloc(262144 * 2);
  short* BtE  = (short*)alloc(32768 * 2);
  short* BtW2 = (short*)alloc(131072 * 2);
  short* BtRZ = (short*)alloc(262144 * 2);
  short* BtHW = (short*)alloc(131072 * 2);
  int* counts = (int*)alloc(NNODES * 4);
  int* rs     = (int*)alloc((NNODES + 1) * 4);
  int* cursor = (int*)alloc(NNODES * 4);
  int* ceid   = (int*)alloc(E_EDGES * 4);
  int* csrc   = (int*)alloc(E_EDGES * 4);
  float* g    = (float*)alloc(512 * 4);
  off = (off + 255) & ~(size_t)255;
  size_t avail = ws_size > off ? ws_size - off : 0;
  short* E1 = (short*)(base + off);

  // E1 chunking: full is 268 MB (iteration-invariant, compute once). If ws
  // can't hold it (measured harness ws = 256 MiB), recompute per-iter in
  // chunks sized to stay L3-resident between e1_gemm and edge_kernel.
  size_t e1_full = (size_t)E_EDGES * 2 * MLPH * 2;
  int nchunks = 1;
  size_t cap_edges = E_EDGES;
  if (avail < e1_full){
    nchunks = 0;
    for (int nc = 2; nc <= 64; nc <<= 1){
      size_t cap = (size_t)((double)E_EDGES / nc * 1.25) + 256;
      if (cap * 2 * MLPH * 2 <= avail){ nchunks = nc; cap_edges = cap; break; }
    }
    if (!nchunks){ nchunks = 64; cap_edges = avail / (2 * MLPH * 2); }
  }

  dim3 blk(256);

  // ------------------------------- prep ----------------------------------
  hipMemsetAsync(g,  0, 512 * 4, stream);
  hipMemsetAsync(counts, 0, NNODES * 4, stream);
  prep_weights<<<3200, blk, 0, stream>>>(W1, W2, Wr, Ur, Wz, Uz, Wh, Uh,
                                         BtP, BtE, BtW2, BtRZ, BtHW);
  cvt_ef<<<(E_EDGES * 2 * EDIM) / (256 * 8), blk, 0, stream>>>(ef, ebf);
  count_kernel<<<512, blk, 0, stream>>>(edst, counts);
  scan_kernel<<<1, 1024, 0, stream>>>(counts, rs, cursor);
  fill_kernel<<<512, blk, 0, stream>>>(edst, esrc, cursor, ceid, csrc);

  auto launch_e1 = [&](int n0, int n1, size_t capE){
    int gx = (int)((2 * capE + 127) / 128);
    e1_gemm<<<dim3(gx, MLPH / 128), blk, 0, stream>>>(
        ebf, BtE, E1, b1, ceid, rs, n0, n1);
  };
  if (nchunks == 1) launch_e1(0, NNODES, E_EDGES);   // iteration-invariant

  // ----------------------------- iterations ------------------------------
  const int npc = NNODES / nchunks;
  for (int it = 0; it < NIT; ++it){
    const short* Pin = (it == 1) ? PA : PB;
    short* Po = (it == 0) ? PA : ((it == 1) ? PB : PA);
    if (nchunks == 1){
      if (it == 0) edge_kernel<false><<<NNODES, blk, 0, stream>>>(Pin, E1, csrc, rs, S, 0);
      else         edge_kernel<true ><<<NNODES, blk, 0, stream>>>(Pin, E1, csrc, rs, S, 0);
    } else {
      for (int c = 0; c < nchunks; ++c){
        launch_e1(c * npc, (c + 1) * npc, cap_edges);
        if (it == 0) edge_kernel<false><<<npc, blk, 0, stream>>>(Pin, E1, csrc, rs, S, c * npc);
        else         edge_kernel<true ><<<npc, blk, 0, stream>>>(Pin, E1, csrc, rs, S, c * npc);
      }
    }
    if (it == 0)
      node_update<0><<<NB / RB, blk, 0, stream>>>(S, Po, m, h, g,
          BtW2, BtRZ, BtHW, BtP, counts, b2, br, bz, bh);
    else if (it == 1)
      node_update<1><<<NB / RB, blk, 0, stream>>>(S, Po, m, h, g,
          BtW2, BtRZ, BtHW, BtP, counts, b2, br, bz, bh);
    else
      node_update<2><<<NB / RB, blk, 0, stream>>>(S, Po, m, h, g,
          BtW2, BtRZ, BtHW, BtP, counts, b2, br, bz, bh);
  }

  // ------------------------------ readout --------------------------------
  readout2<<<1, blk, 0, stream>>>(g, Wo, bo, (float*)d_out);
}